// Round 21
// baseline (247.591 us; speedup 1.0000x reference)
//
#include <hip/hip_runtime.h>
#include <hip/hip_bf16.h>
#include <math.h>

// Problem constants: B=2, H=W=128, C=256, HEADS=8, D=32, N=16384, M=B*N=32768
typedef short bf16x8 __attribute__((ext_vector_type(8)));
typedef float f32x4 __attribute__((ext_vector_type(4)));

#define MFMA16(a,b,c) __builtin_amdgcn_mfma_f32_16x16x32_bf16(a,b,c,0,0,0)

__device__ inline short f2bf(float f){
  union{ __hip_bfloat16 h; short s; } u;
  u.h = __float2bfloat16(f);
  return u.s;
}
__device__ inline float bf2f(short s){
  uint32_t u = ((uint32_t)(uint16_t)s) << 16;
  return __builtin_bit_cast(float, u);
}
__device__ inline void store8bf(short* dst, float4 a, float4 b){
  union{ short s[8]; int4 q; } u;
  u.s[0]=f2bf(a.x); u.s[1]=f2bf(a.y); u.s[2]=f2bf(a.z); u.s[3]=f2bf(a.w);
  u.s[4]=f2bf(b.x); u.s[5]=f2bf(b.y); u.s[6]=f2bf(b.z); u.s[7]=f2bf(b.w);
  *(int4*)dst = u.q;
}

// async global->LDS, 16B per lane. LDS dest must be wave-uniform; HW adds lane*16.
__device__ inline void gld16(const void* g, void* l){
  __builtin_amdgcn_global_load_lds(
      (const __attribute__((address_space(1))) unsigned int*)g,
      (__attribute__((address_space(3))) unsigned int*)l, 16, 0, 0);
}

// raw barrier without vmcnt(0) drain; asm memory clobbers pin compiler ordering
#define BARC() do{ asm volatile("":::"memory"); __builtin_amdgcn_s_barrier(); \
                   asm volatile("":::"memory"); }while(0)

// ---------- generic f32 -> bf16 convert (fallback path) ----------
__global__ __launch_bounds__(256) void k_cvt(const float* __restrict__ src, short* __restrict__ dst, int n){
  int i = blockIdx.x*256 + threadIdx.x;
  if(i < n) dst[i] = f2bf(src[i]);
}

// ---------- sum ncpy cov copies (stride 917504 floats) -> bf16 ----------
__global__ __launch_bounds__(256) void k_cvtN(const float* __restrict__ src, short* __restrict__ dst,
                                              int n, int ncpy){
  int i = blockIdx.x*256 + threadIdx.x;
  if(i >= n) return;
  float s = src[i];
  for(int c=1;c<ncpy;++c) s += src[i + (size_t)c*917504];
  dst[i] = f2bf(s);
}

// ---------- transpose-convert the 4 Wv matrices (fallback path) ----------
__global__ __launch_bounds__(256) void k_wvt(const float* __restrict__ wm, const float* __restrict__ w2,
                                             const float* __restrict__ w4, const float* __restrict__ w8,
                                             short* __restrict__ wvT){
  int t = blockIdx.x*256 + threadIdx.x;      // 4*65536 total
  int br = t >> 16; int rem = t & 65535; int a = rem >> 8, j = rem & 255;
  const float* w = (br==0)? wm : (br==1)? w2 : (br==2)? w4 : w8;
  wvT[t] = f2bf(w[j*256 + a]);
}

// ---------- transpose conv weights (fallback path) ----------
__global__ __launch_bounds__(256) void k_wT(const float* __restrict__ w1, const float* __restrict__ w2,
                                            float* __restrict__ wT){
  int t = blockIdx.x*256 + threadIdx.x;      // 2*9*256 = 4608
  if(t >= 4608) return;
  int cv = t / 2304; int rem = t % 2304; int tap = rem >> 8; int c = rem & 255;
  const float* w = cv ? w2 : w1;
  wT[t] = w[c*9 + tap];
}

// ---------- merged prep: WvmB cvt (blocks 0..255), WvT transpose (256..1279), wT (1280..1297) ----------
__global__ __launch_bounds__(256) void k_prep(const float* __restrict__ Wvm, const float* __restrict__ Wv2,
                                              const float* __restrict__ Wv4, const float* __restrict__ Wv8,
                                              const float* __restrict__ Wp1, const float* __restrict__ Wp2,
                                              short* __restrict__ WvmB, short* __restrict__ wvT,
                                              float* __restrict__ wT){
  int bx = blockIdx.x, t = threadIdx.x;
  if(bx < 256){
    int i = bx*256 + t;
    WvmB[i] = f2bf(Wvm[i]);
  } else if(bx < 1280){
    int i = (bx-256)*256 + t;                // 0..262143
    int br = i >> 16; int rem = i & 65535; int a = rem >> 8, j = rem & 255;
    const float* w = (br==0)? Wvm : (br==1)? Wv2 : (br==2)? Wv4 : Wv8;
    wvT[i] = f2bf(w[j*256 + a]);
  } else {
    int i = (bx-1280)*256 + t;               // 0..4607
    if(i < 4608){
      int cv = i / 2304; int rem = i % 2304; int tap = rem >> 8; int c = rem & 255;
      const float* w = cv ? Wp2 : Wp1;
      wT[i] = w[c*9 + tap];
    }
  }
}

// ---------- swizzled LDS helpers for [64][256] bf16 A-tiles ----------
__device__ inline void at_write4(short* base, int row, int l, float4 v){
  union{ short s[4]; int2 q; } u;
  u.s[0]=f2bf(v.x); u.s[1]=f2bf(v.y); u.s[2]=f2bf(v.z); u.s[3]=f2bf(v.w);
  int byte = row*512 + 8*l;
  byte ^= ((row&7)<<4);
  *(int2*)((char*)base + byte) = u.q;
}
// column variant: c4 = column in units of 4 bf16
__device__ inline void at_write4c(short* base, int row, int c4, float4 v){
  union{ short s[4]; int2 q; } u;
  u.s[0]=f2bf(v.x); u.s[1]=f2bf(v.y); u.s[2]=f2bf(v.z); u.s[3]=f2bf(v.w);
  int byte = row*512 + c4*8;
  byte ^= ((row&7)<<4);
  *(int2*)((char*)base + byte) = u.q;
}
__device__ inline bf16x8 at_read8(const short* base, int row, int kk, int q){
  int byte = row*512 + kk*64 + q*16;
  byte ^= ((row&7)<<4);
  return *(const bf16x8*)((const char*)base + byte);
}

// ---------- pack x-inputs to tiled layout XT2[sb][ntile][256c][32n] bf16, 16KB tiles ----------
// TWO tiles per block (64 rows). Register transpose -> LDS staging at final tile layout
// (LDS-only XOR swizzle byte^=((byte>>8)&7)<<4 on BOTH write and read) -> linear coalesced
// copy-out. Global layout: chunk pos = hi ^ ((c>>1)&3) within each 64B c-row.
__global__ __launch_bounds__(256) void k_pack(const float* __restrict__ x2, const float* __restrict__ x4,
                                              const float* __restrict__ x8, const float* __restrict__ y,
                                              short* __restrict__ xt, int sb0){
  int sb = blockIdx.z + sb0; int s = sb >> 1, b = sb & 1;
  const float* src = ((s==0)? y : (s==1)? x2 : (s==2)? x4 : x8) + (size_t)b*16384*256;
  __shared__ int4 tile4[2048];               // 2 x 16KB
  char* tile = (char*)tile4;
  int t = threadIdx.x;
  int cg = t & 63, ng = t >> 6;              // channel group (4c), n-subgroup (8n)
  int n0 = blockIdx.x*64;
  const float* p0 = src + (size_t)(n0 + ng*8)*256 + cg*4;
  const float* p1 = src + (size_t)(n0 + 32 + ng*8)*256 + cg*4;
  union{ float4 q; float f[4]; } v0[8], v1[8];
  #pragma unroll
  for(int r=0;r<8;++r) v0[r].q = *(const float4*)(p0 + (size_t)r*256);
  #pragma unroll
  for(int r=0;r<8;++r) v1[r].q = *(const float4*)(p1 + (size_t)r*256);
  #pragma unroll
  for(int i=0;i<4;++i){
    int c = cg*4 + i;
    int byte = c*64 + ((ng ^ ((c>>1)&3))<<4);
    byte ^= ((byte>>8)&7)<<4;                // LDS-only swizzle (bits 8-10; tile base bit14 unaffected)
    union{ short s8[8]; int4 q; } u;
    #pragma unroll
    for(int r=0;r<8;++r) u.s8[r] = f2bf(v0[r].f[i]);
    *(int4*)(tile + byte) = u.q;
    #pragma unroll
    for(int r=0;r<8;++r) u.s8[r] = f2bf(v1[r].f[i]);
    *(int4*)(tile + 16384 + byte) = u.q;
  }
  __syncthreads();
  short* outb = xt + ((size_t)sb*512 + blockIdx.x*2)*8192;
  #pragma unroll
  for(int ti=0; ti<2; ++ti)
    #pragma unroll
    for(int j=0;j<4;++j){
      int addr = j*4096 + t*16;
      int sa = addr ^ (((addr>>8)&7)<<4);
      *(int4*)((char*)outb + ti*16384 + addr) = *(const int4*)(tile + ti*16384 + sa);
    }
}

// ---------- pack y + fused vm = y @ Wvm^T ----------
__global__ __launch_bounds__(256) void k_packy(const float* __restrict__ y, const short* __restrict__ wB,
                                               short* __restrict__ xt, short* __restrict__ vm){
  int b = blockIdx.z;
  const float* src = y + (size_t)b*16384*256;
  __shared__ int4 tile4[2048];               // 2 x 16KB cov-layout tiles
  __shared__ short at[64*256];               // 32KB [n][c] tile
  char* tile = (char*)tile4;
  int t = threadIdx.x;
  int cg = t & 63, ng = t >> 6;
  int n0 = blockIdx.x*64;
  const float* p0 = src + (size_t)(n0 + ng*8)*256 + cg*4;
  const float* p1 = src + (size_t)(n0 + 32 + ng*8)*256 + cg*4;
  union{ float4 q; float f[4]; } v0[8], v1[8];
  #pragma unroll
  for(int r=0;r<8;++r) v0[r].q = *(const float4*)(p0 + (size_t)r*256);
  #pragma unroll
  for(int r=0;r<8;++r) v1[r].q = *(const float4*)(p1 + (size_t)r*256);
  #pragma unroll
  for(int i=0;i<4;++i){
    int c = cg*4 + i;
    int byte = c*64 + ((ng ^ ((c>>1)&3))<<4);
    byte ^= ((byte>>8)&7)<<4;
    union{ short s8[8]; int4 q; } u;
    #pragma unroll
    for(int r=0;r<8;++r) u.s8[r] = f2bf(v0[r].f[i]);
    *(int4*)(tile + byte) = u.q;
    #pragma unroll
    for(int r=0;r<8;++r) u.s8[r] = f2bf(v1[r].f[i]);
    *(int4*)(tile + 16384 + byte) = u.q;
  }
  #pragma unroll
  for(int r=0;r<8;++r){
    at_write4c(at, ng*8 + r, cg, v0[r].q);
    at_write4c(at, 32 + ng*8 + r, cg, v1[r].q);
  }
  __syncthreads();
  // XT2 copy-out
  short* outb = xt + ((size_t)b*512 + blockIdx.x*2)*8192;
  #pragma unroll
  for(int ti=0; ti<2; ++ti)
    #pragma unroll
    for(int j=0;j<4;++j){
      int addr = j*4096 + t*16;
      int sa = addr ^ (((addr>>8)&7)<<4);
      *(int4*)((char*)outb + ti*16384 + addr) = *(const int4*)(tile + ti*16384 + sa);
    }
  // vm compute (k_vm body)
  int l = t & 63, w = t >> 6;
  size_t m0 = (size_t)b*16384 + n0;
  f32x4 acc[4][4];
  #pragma unroll
  for(int i=0;i<4;++i)
    #pragma unroll
    for(int n2=0;n2<4;++n2) acc[i][n2] = (f32x4){0.f,0.f,0.f,0.f};
  #pragma unroll
  for(int kk=0; kk<8; ++kk){
    bf16x8 a[4];
    #pragma unroll
    for(int rt=0;rt<4;++rt) a[rt] = at_read8(at, rt*16 + (l&15), kk, l>>4);
    #pragma unroll
    for(int nt=0;nt<4;++nt){
      int bc = (w*4+nt)*16 + (l&15);
      bf16x8 bb = *(const bf16x8*)&wB[(size_t)bc*256 + kk*32 + 8*(l>>4)];
      #pragma unroll
      for(int rt=0;rt<4;++rt) acc[rt][nt] = MFMA16(a[rt], bb, acc[rt][nt]);
    }
  }
  #pragma unroll
  for(int rt=0;rt<4;++rt)
    #pragma unroll
    for(int nt=0;nt<4;++nt)
      #pragma unroll
      for(int r=0;r<4;++r){
        size_t row = m0 + rt*16 + 4*(l>>4) + r;
        int col = (w*4+nt)*16 + (l&15);
        vm[row*256 + col] = f2bf(acc[rt][nt][r]);
      }
}

// fragment read from a staged 16KB tile (swizzle pre-applied by pack)
__device__ inline bf16x8 tfrag(const short* base, int c, int hi){
  int byte = c*64 + ((hi ^ ((c>>1)&3))<<4);
  return *(const bf16x8*)((const char*)base + byte);
}

// ---------- gram jobs: cov[jb][U_ch][V_ch] = sum_n U[n,i] V[n,j], from tiled XT2 ----------
__global__ __launch_bounds__(512) void k_cov(const short* __restrict__ xt, float* __restrict__ covF,
                                             int plain){
  int jb = blockIdx.x;               // 0..13
  int ck = blockIdx.y;               // 0..15 : n-chunk of 1024 (16 phases of 2 tiles)
  int j = jb >> 1, b = jb & 1;
  int t = threadIdx.x, l = t & 63, w = t >> 6;
  int lr = l & 15, hi = l >> 4;
  int wr = w >> 1, wc = w & 1;       // wave row-group (64 rows), col-group (128 cols)
  __shared__ short lds2[2][32768];   // 2 phase-buffers x (2 tiles x 16KB) = 128KB
  int su = (j < 4) ? 0 : (j - 3);
  int sv = (j == 0) ? 0 : ((j < 4) ? j : (j - 3));
  int sym = (su == sv);
  const short* Ug = xt + (size_t)(su*2+b)*512*8192;
  const short* Vg = xt + (size_t)(sv*2+b)*512*8192;
  int nt0 = ck*32;

  f32x4 acc[4][8];
  #pragma unroll
  for(int i=0;i<4;++i)
    #pragma unroll
    for(int n2=0;n2<8;++n2) acc[i][n2] = (f32x4){0.f,0.f,0.f,0.f};

  #define STAGE_T_S(bufi, tt, kk) do{                                           \
    const short* Ut_ = Ug + (size_t)(nt0+(kk))*8192;                            \
    short* dst_ = &lds2[bufi][(tt)*16384];                                      \
    _Pragma("unroll")                                                           \
    for(int i_=0;i_<2;++i_){ int ch_ = w*2+i_;                                  \
      gld16(Ut_ + ch_*512 + l*8, dst_ + ch_*512); }                             \
  }while(0)
  #define STAGE_T_A(bufi, tt, kk) do{                                           \
    const short* Ut_ = Ug + (size_t)(nt0+(kk))*8192;                            \
    const short* Vt_ = Vg + (size_t)(nt0+(kk))*8192;                            \
    short* dst_ = &lds2[bufi][(tt)*16384];                                      \
    _Pragma("unroll")                                                           \
    for(int i_=0;i_<4;++i_){ int ch_ = w*4+i_;                                  \
      const short* g_ = (ch_<16) ? (Ut_ + ch_*512 + l*8)                        \
                                 : (Vt_ + (ch_-16)*512 + l*8);                  \
      gld16(g_, dst_ + ch_*512); }                                              \
  }while(0)
  #define COMPUTE_T(bufp, vofs) do{                                             \
    const short* Ub_ = bufp;                                                    \
    const short* Vb_ = Ub_ + (vofs);                                            \
    bf16x8 a_[4];                                                               \
    _Pragma("unroll")                                                           \
    for(int rt_=0;rt_<4;++rt_)                                                  \
      a_[rt_] = tfrag(Ub_, wr*64 + rt_*16 + lr, hi);                            \
    _Pragma("unroll")                                                           \
    for(int nt_=0;nt_<8;++nt_){                                                 \
      bf16x8 bb_ = tfrag(Vb_, wc*128 + nt_*16 + lr, hi);                        \
      _Pragma("unroll")                                                         \
      for(int rt_=0;rt_<4;++rt_)                                                \
        acc[rt_][nt_] = MFMA16(a_[rt_], bb_, acc[rt_][nt_]);                    \
    }                                                                           \
  }while(0)

  if(sym){
    STAGE_T_S(0,0,0); STAGE_T_S(0,1,1); STAGE_T_S(1,0,2); STAGE_T_S(1,1,3);
    asm volatile("s_waitcnt vmcnt(4)":::"memory");   // phase0 landed; phase1 in flight
    BARC();
    #pragma unroll 1
    for(int p=0;p<16;++p){
      const short* base = &lds2[p&1][0];
      COMPUTE_T(base, 0);
      COMPUTE_T(base + 16384, 0);
      if(p==15) break;
      BARC();
      if(p < 14){
        STAGE_T_S(p&1, 0, 2*p+4); STAGE_T_S(p&1, 1, 2*p+5);
        asm volatile("s_waitcnt vmcnt(4)":::"memory");   // phase p+1 landed
      } else {
        asm volatile("s_waitcnt vmcnt(0)":::"memory");
      }
      BARC();
    }
  } else {
    STAGE_T_A(0,0,0); STAGE_T_A(0,1,1); STAGE_T_A(1,0,2); STAGE_T_A(1,1,3);
    asm volatile("s_waitcnt vmcnt(8)":::"memory");
    BARC();
    #pragma unroll 1
    for(int p=0;p<16;++p){
      const short* base = &lds2[p&1][0];
      COMPUTE_T(base, 8192);
      COMPUTE_T(base + 16384, 8192);
      if(p==15) break;
      BARC();
      if(p < 14){
        STAGE_T_A(p&1, 0, 2*p+4); STAGE_T_A(p&1, 1, 2*p+5);
        asm volatile("s_waitcnt vmcnt(8)":::"memory");
      } else {
        asm volatile("s_waitcnt vmcnt(0)":::"memory");
      }
      BARC();
    }
  }
  #undef STAGE_T_S
  #undef STAGE_T_A
  #undef COMPUTE_T

  if(plain){
    float* cov = covF + (size_t)ck*917504 + (size_t)jb*65536;
    #pragma unroll
    for(int rt=0;rt<4;++rt)
      #pragma unroll
      for(int nt=0;nt<8;++nt)
        #pragma unroll
        for(int r=0;r<4;++r){
          int row = wr*64 + rt*16 + 4*hi + r;
          int col = wc*128 + nt*16 + lr;
          cov[(size_t)row*256 + col] = acc[rt][nt][r];
        }
  } else {
    float* cov = covF + (size_t)jb*65536;
    #pragma unroll
    for(int rt=0;rt<4;++rt)
      #pragma unroll
      for(int nt=0;nt<8;++nt)
        #pragma unroll
        for(int r=0;r<4;++r){
          int row = wr*64 + rt*16 + 4*hi + r;
          int col = wc*128 + nt*16 + lr;
          atomicAdd(&cov[(size_t)row*256 + col], acc[rt][nt][r]);
        }
  }
}

// ---------- helpers for 32x256 and 32x32 MFMA products in k_attn ----------
__device__ inline void mm_32x256(const short (*wA)[264], const short* __restrict__ covbf,
                                 short (*tmp)[264], int t){
  int l = t & 63, w = t >> 6;
  int mt = w >> 1, ntb = (w & 1)*8;
  f32x4 acc[8];
  #pragma unroll
  for(int i=0;i<8;++i) acc[i] = (f32x4){0.f,0.f,0.f,0.f};
  #pragma unroll
  for(int kk=0; kk<8; ++kk){
    bf16x8 a = *(const bf16x8*)&wA[16*mt + (l&15)][kk*32 + 8*(l>>4)];
    #pragma unroll
    for(int n=0; n<8; ++n){
      int j = (ntb+n)*16 + (l&15);
      bf16x8 bb = *(const bf16x8*)&covbf[(size_t)j*256 + kk*32 + 8*(l>>4)];
      acc[n] = MFMA16(a, bb, acc[n]);
    }
  }
  #pragma unroll
  for(int n=0;n<8;++n)
    #pragma unroll
    for(int r=0;r<4;++r)
      tmp[16*mt + 4*(l>>4) + r][(ntb+n)*16 + (l&15)] = f2bf(acc[n][r]);
}
__device__ inline void mm_32x32(const short (*A)[264], const short (*Bw)[264], float (*M)[33], int t){
  int l = t & 63, w = t >> 6;
  int mt = w >> 1, nt = w & 1;
  f32x4 acc = (f32x4){0.f,0.f,0.f,0.f};
  #pragma unroll
  for(int kk=0; kk<8; ++kk){
    bf16x8 a = *(const bf16x8*)&A[16*mt + (l&15)][kk*32 + 8*(l>>4)];
    bf16x8 b = *(const bf16x8*)&Bw[16*nt + (l&15)][kk*32 + 8*(l>>4)];
    acc = MFMA16(a, b, acc);
  }
  #pragma unroll
  for(int r=0;r<4;++r)
    M[16*mt + 4*(l>>4) + r][16*nt + (l&15)] = acc[r];
}

// ---------- attention matrices: G = Wk_h * Cov_xy * Wq_h^T, norms from Cxx/Cyy diag, softmax -> A ----------
__global__ __launch_bounds__(256) void k_attn(
    const float* __restrict__ Wq, const float* __restrict__ Wkm, const float* __restrict__ Wk2,
    const float* __restrict__ Wk4, const float* __restrict__ Wk8,
    const float* __restrict__ rsm, const float* __restrict__ rs2, const float* __restrict__ rs4,
    const short* __restrict__ covB, float* __restrict__ Aout){
  int h = blockIdx.x, b = blockIdx.y, br = blockIdx.z;
  int t = threadIdx.x;
  __shared__ short wk[32][264], wq[32][264], tmp[32][264];
  __shared__ float Ml[32][33];
  __shared__ float nrm[64];
  const float* Wk = (br==0)? Wkm : (br==1)? Wk2 : (br==2)? Wk4 : Wk8;
  {
    int d = t >> 3, c0 = (t & 7)*32;
    const float* pk = Wk + (size_t)(h*32+d)*256 + c0;
    const float* pq = Wq + (size_t)(h*32+d)*256 + c0;
    #pragma unroll
    for(int i=0;i<32;i+=8){
      float4 a1 = *(const float4*)(pk+i), a2 = *(const float4*)(pk+i+4);
      store8bf(&wk[d][c0+i], a1, a2);
      float4 b1 = *(const float4*)(pq+i), b2 = *(const float4*)(pq+i+4);
      store8bf(&wq[d][c0+i], b1, b2);
    }
  }
  __syncthreads();
  const short* cxy = covB + (size_t)(br*2+b)*65536;
  const short* cxx = (br==0)? cxy : covB + (size_t)(8 + (br-1)*2 + b)*65536;
  const short* cyy = covB + (size_t)b*65536;
  // k norms^2
  mm_32x256(wk, cxx, tmp, t); __syncthreads();
  mm_32x32(tmp, wk, Ml, t);   __syncthreads();
  if(t < 32) nrm[t] = Ml[t][t];
  __syncthreads();
  // q norms^2
  mm_32x256(wq, cyy, tmp, t); __syncthreads();
  mm_32x32(tmp, wq, Ml, t);   __syncthreads();
  if(t < 32) nrm[32+t] = Ml[t][t];
  __syncthreads();
  // G
  mm_32x256(wk, cxy, tmp, t); __syncthreads();
  mm_32x32(tmp, wq, Ml, t);   __syncthreads();
  if(t < 32){
    int d = t;
    const float* rs = (br==0)? rsm : (br==1)? rs2 : rs4;  // br==3 uses rescale4 (faithful to source)
    float rsv = rs[h];
    float invk = 1.f / fmaxf(sqrtf(fmaxf(nrm[d], 0.f)), 1e-12f);
    float lg[32]; float mx = -1e30f;
    #pragma unroll
    for(int e=0;e<32;++e){
      float invq = 1.f / fmaxf(sqrtf(fmaxf(nrm[32+e], 0.f)), 1e-12f);
      float v = Ml[d][e] * invk * invq * rsv;
      lg[e] = v; mx = fmaxf(mx, v);
    }
    float sum = 0.f;
    #pragma unroll
    for(int e=0;e<32;++e){ lg[e] = expf(lg[e]-mx); sum += lg[e]; }
    float inv = 1.f/sum;
    float* Ao = Aout + ((size_t)((br*2+b)*8 + h))*1024 + d*32;
    #pragma unroll
    for(int e=0;e<32;++e) Ao[e] = lg[e]*inv;
  }
}

// ---------- fold: Qf[br][b] = (Wproj ⊙head A) * Wv_br   (256x256 bf16 each) ----------
__global__ __launch_bounds__(256) void k_qfold(const float* __restrict__ Wproj, const float* __restrict__ Ain,
                                               const short* __restrict__ wvT, short* __restrict__ qf){
  int cg = blockIdx.x, b = blockIdx.y, br = blockIdx.z;
  int t = threadIdx.x;
  __shared__ float Al[8*1036];
  __shared__ short pl[32][264];
  const float* Ag = Ain + (size_t)((br*2+b)*8)*1024;
  for(int i=t; i<8192; i+=256){
    int hh = i >> 10, dd = (i >> 5) & 31, ee = i & 31;
    Al[hh*1036 + dd*32 + ee] = Ag[i];
  }
  __syncthreads();
  {
    int c = cg*32 + (t >> 3), h = t & 7;
    const float* wpr = Wproj + (size_t)c*256 + h*32;
    float wp[32];
    #pragma unroll
    for(int i=0;i<32;i+=4){
      float4 v = *(const float4*)(wpr+i);
      wp[i]=v.x; wp[i+1]=v.y; wp[i+2]=v.z; wp[i+3]=v.w;
    }
    float pv[32];
    #pragma unroll
    for(int e=0;e<32;++e) pv[e]=0.f;
    const float* Ah = Al + h*1036;
    #pragma unroll
    for(int d=0; d<32; ++d){
      float wpd = wp[d];
      #pragma unroll
      for(int e=0;e<32;e+=4){
        float4 av = *(const float4*)&Ah[d*32+e];
        pv[e]   += wpd*av.x; pv[e+1] += wpd*av.y;
        pv[e+2] += wpd*av.z; pv[e+3] += wpd*av.w;
      }
    }
    #pragma unroll
    for(int e=0;e<32;++e) pl[t>>3][h*32+e] = f2bf(pv[e]);
  }
  __syncthreads();
  {
    int l = t & 63, w = t >> 6, mt = w >> 1, ntb = (w & 1)*8;
    const short* wvt = wvT + (size_t)br*65536;
    f32x4 acc[8];
    #pragma unroll
    for(int i=0;i<8;++i) acc[i] = (f32x4){0.f,0.f,0.f,0.f};
    #pragma unroll
    for(int kk=0; kk<8; ++kk){
      bf16x8 a = *(const bf16x8*)&pl[16*mt + (l&15)][kk*32 + 8*(l>>4)];
      #pragma unroll
      for(int n=0;n<8;++n){
        int arow = (ntb+n)*16 + (l&15);
        bf16x8 bb = *(const bf16x8*)&wvt[(size_t)arow*256 + kk*32 + 8*(l>>4)];
        acc[n] = MFMA16(a, bb, acc[n]);
      }
    }
    short* qfp = qf + (size_t)(br*2+b)*65536;
    #pragma unroll
    for(int n=0;n<8;++n)
      #pragma unroll
      for(int r=0;r<4;++r){
        int row = cg*32 + 16*mt + 4*(l>>4) + r;
        int col = (ntb+n)*16 + (l&15);
        qfp[(size_t)row*256 + col] = f2bf(acc[n][r]);
      }
  }
}

// ---------- vm = y @ Wvm^T  (fallback path) ----------
__global__ __launch_bounds__(256,2) void k_vm(const float* __restrict__ y, const short* __restrict__ wB,
                                              short* __restrict__ vm){
  int t = threadIdx.x, l = t & 63, w = t >> 6;
  size_t m0 = (size_t)blockIdx.x*64;
  __shared__ short at[64*256];
  #pragma unroll
  for(int rr=0; rr<16; ++rr){
    int row = w*16 + rr;
    float4 v = *(const float4*)(y + (m0+row)*256 + 4*l);
    at_write4(at, row, l, v);
  }
  __syncthreads();
  f32x4 acc[4][4];
  #pragma unroll
  for(int i=0;i<4;++i)
    #pragma unroll
    for(int n2=0;n2<4;++n2) acc[i][n2] = (f32x4){0.f,0.f,0.f,0.f};
  #pragma unroll
  for(int kk=0; kk<8; ++kk){
    bf16x8 a[4];
    #pragma unroll
    for(int rt=0;rt<4;++rt) a[rt] = at_read8(at, rt*16 + (l&15), kk, l>>4);
    #pragma unroll
    for(int nt=0;nt<4;++nt){
      int bc = (w*4+nt)*16 + (l&15);
      bf16x8 bb = *(const bf16x8*)&wB[(size_t)bc*256 + kk*32 + 8*(l>>4)];
      #pragma unroll
      for(int rt=0;rt<4;++rt) acc[rt][nt] = MFMA16(a[rt], bb, acc[rt][nt]);
    }
  }
  #pragma unroll
  for(int rt=0;rt<4;++rt)
    #pragma unroll
    for(int nt=0;nt<4;++nt)
      #pragma unroll
      for(int r=0;r<4;++r){
        size_t row = m0 + rt*16 + 4*(l>>4) + r;
        int col = (w*4+nt)*16 + (l&15);
        vm[row*256 + col] = f2bf(acc[rt][nt][r]);
      }
}

// ---------- FUSED depthwise 3x3 conv x2 (conv1+GELU -> LDS -> conv2), NHWC ----------
// Block: 512 threads = 32 ch-groups x 16 pixels (4x4 tile). Phase 1 computes conv1+GELU
// (bf16-rounded, matching the old GBUF store exactly) on the 6x6 halo region into LDS;
// out-of-image positions store 0 (= zero padding, gelu(0)=0). Phase 2 computes conv2
// from LDS and writes POS. Eliminates the GBUF round-trip and one launch.
__global__ __launch_bounds__(512) void k_convf(const short* __restrict__ vmIn,
                                               const float* __restrict__ wT,
                                               short* __restrict__ pos){
  int b = blockIdx.z;
  int x0 = blockIdx.x*4, y0 = blockIdx.y*4;
  int t = threadIdx.x;
  __shared__ short g1[36*256];               // [gy*6+gx][256ch], 18KB
  const float* w1 = wT;
  const float* w2 = wT + 2304;
  // phase 1: conv1+gelu at image pos (x0-1+gx, y0-1+gy), gx,gy in [0,6)
  #pragma unroll 1
  for(int i=0;i<3;++i){
    int tau = t + i*512;
    if(tau < 1152){
      int cg1 = tau & 31, p = tau >> 5;      // p in [0,36)
      int gy = p / 6, gx = p % 6;
      int ix = x0 - 1 + gx, iy = y0 - 1 + gy;
      int c0 = cg1*8;
      float acc[8];
      #pragma unroll
      for(int q=0;q<8;++q) acc[q]=0.f;
      if(ix >= 0 && ix < 128 && iy >= 0 && iy < 128){
        #pragma unroll
        for(int ky=0; ky<3; ++ky){
          int sy = iy + ky - 1;
          if(sy < 0 || sy > 127) continue;
          #pragma unroll
          for(int kx=0; kx<3; ++kx){
            int sx = ix + kx - 1;
            if(sx < 0 || sx > 127) continue;
            const float* wp = w1 + (ky*3+kx)*256 + c0;
            float4 a0 = *(const float4*)wp;
            float4 a1 = *(const float4*)(wp+4);
            const short* pv = vmIn + ((size_t)(((b<<7)+sy)<<7) + sx)*256 + c0;
            union{ int4 q; short s[8]; } u;
            u.q = *(const int4*)pv;
            acc[0]+=bf2f(u.s[0])*a0.x; acc[1]+=bf2f(u.s[1])*a0.y;
            acc[2]+=bf2f(u.s[2])*a0.z; acc[3]+=bf2f(u.s[3])*a0.w;
            acc[4]+=bf2f(u.s[4])*a1.x; acc[5]+=bf2f(u.s[5])*a1.y;
            acc[6]+=bf2f(u.s[6])*a1.z; acc[7]+=bf2f(u.s[7])*a1.w;
          }
        }
        #pragma unroll
        for(int q=0;q<8;++q)
          acc[q] = 0.5f*acc[q]*(1.f + erff(acc[q]*0.70710678118654752f));
      }
      union{ int4 q; short s[8]; } o;
      #pragma unroll
      for(int q=0;q<8;++q) o.s[q] = f2bf(acc[q]);
      *(int4*)&g1[p*256 + c0] = o.q;
    }
  }
  __syncthreads();
  // phase 2: conv2 at (x0+px, y0+py)
  int cg2 = t & 31, pidx = t >> 5;           // pidx in [0,16)
  int px = pidx & 3, py = pidx >> 2;
  int c0 = cg2*8;
  float acc[8];
  #pragma unroll
  for(int q=0;q<8;++q) acc[q]=0.f;
  #pragma unroll
  for(int ky=0; ky<3; ++ky){
    #pragma unroll
    for(int kx=0; kx<3; ++kx){
      const float* wp = w2 + (ky*3+kx)*256 + c0;
      float4 a0 = *(const float4*)wp;
      float4 a1 = *(const float4*)(wp+4);
      int gp = (py+ky)*6 + (px+kx);
      union{ int4 q; short s[8]; } u;
      u.q = *(const int4*)&g1[gp*256 + c0];
      acc[0]+=bf2f(u.s[0])*a0.x; acc[1]+=bf2f(u.s[1])*a0.y;
      acc[2]+=bf2f(u.s[2])*a0.z; acc[3]+=bf2f(u.s[3])*a0.w;
      acc[4]+=bf2f(u.s[4])*a1.x; acc[5]+=bf2f(u.s[5])*a1.y;
      acc[6]+=bf2f(u.s[6])*a1.z; acc[7]+=bf2f(u.s[7])*a1.w;
    }
  }
  union{ int4 q; short s[8]; } o;
  #pragma unroll
  for(int q=0;q<8;++q) o.s[q] = f2bf(acc[q]);
  *(int4*)(pos + ((size_t)(((b<<7)+(y0+py))<<7) + (x0+px))*256 + c0) = o.q;
}

// ---------- final: out = sum_br x_br @ Qf[br][b]^T + bproj + pos ----------
// Double-buffered LDS + register prefetch of next branch; ONE raw barrier per branch
// (lgkmcnt(0) only -- global prefetch stays in flight across the barrier).
__global__ __launch_bounds__(256,2) void k_final(const float* __restrict__ y, const float* __restrict__ x2,
                                                 const float* __restrict__ x4, const float* __restrict__ x8,
                                                 const short* __restrict__ qf, const float* __restrict__ bproj,
                                                 const short* __restrict__ pos, float* __restrict__ out){
  int t = threadIdx.x, l = t & 63, w = t >> 6;
  size_t m0 = (size_t)blockIdx.x*64;
  int b = (int)(m0 >> 14);
  __shared__ short at2[2][64*256];
  f32x4 acc[4][4];
  #pragma unroll
  for(int i=0;i<4;++i)
    #pragma unroll
    for(int n2=0;n2<4;++n2) acc[i][n2] = (f32x4){0.f,0.f,0.f,0.f};
  const float* srcs[4] = {y, x2, x4, x8};
  float4 vreg[16];
  #pragma unroll
  for(int rr=0; rr<16; ++rr)
    vreg[rr] = *(const float4*)(srcs[0] + (m0 + w*16 + rr)*256 + 4*l);
  #pragma unroll 1
  for(int br=0; br<4; ++br){
    short* buf = &at2[br&1][0];
    #pragma unroll
    for(int rr=0; rr<16; ++rr)
      at_write4(buf, w*16 + rr, l, vreg[rr]);
    if(br < 3){
      const float* s = srcs[br+1];
      #pragma unroll
      for(int rr=0; rr<16; ++rr)
        vreg[rr] = *(const float4*)(s + (m0 + w*16 + rr)*256 + 4*l);
    }
    asm volatile("s_waitcnt lgkmcnt(0)":::"memory");   // LDS writes visible
    BARC();                                            // no vmcnt drain: prefetch in flight
    const short* qb = qf + (size_t)(br*2+b)*65536;
    #pragma unroll
    for(int kk=0; kk<8; ++kk){
      bf16x8 a[4];
      #pragma unroll
      for(int rt=0;rt<4;++rt) a[rt] = at_read8(buf, rt*16 + (l&15), kk, l>>4);
      #pragma unroll
      for(int nt=0;nt<4;++nt){
        int bc = (w*4+nt)*16 + (l&15);
        bf16x8 bb = *(const bf16x8*)&qb[(size_t)bc*256 + kk*32 + 8*(l>>4)];
        #pragma unroll
        for(int rt=0;rt<4;++rt) acc[rt][nt] = MFMA16(a[rt], bb, acc[rt][nt]);
      }
    }
  }
  #pragma unroll
  for(int rt=0;rt<4;++rt)
    #pragma unroll
    for(int nt=0;nt<4;++nt)
      #pragma unroll
      for(int r=0;r<4;++r){
        size_t row = m0 + rt*16 + 4*(l>>4) + r;
        int col = (w*4+nt)*16 + (l&15);
        out[row*256 + col] = acc[rt][nt][r] + bproj[col] + bf2f(pos[row*256 + col]);
      }
}

extern "C" void kernel_launch(void* const* d_in, const int* in_sizes, int n_in,
                              void* d_out, int out_size, void* d_ws, size_t ws_size,
                              hipStream_t stream){
  (void)in_sizes; (void)n_in; (void)out_size;
  const float* x2   = (const float*)d_in[0];
  const float* x4   = (const float*)d_in[1];
  const float* x8   = (const float*)d_in[2];
  const float* y    = (const float*)d_in[3];
  const float* Wq   = (const float*)d_in[4];
  const float* Wkm  = (const float*)d_in[5];
  const float* Wvm  = (const float*)d_in[6];
  const float* Wk2  = (const float*)d_in[7];
  const float* Wv2  = (const float*)d_in[8];
  const float* Wk4  = (const float*)d_in[9];
  const float* Wv4  = (const float*)d_in[10];
  const float* Wk8  = (const float*)d_in[11];
  const float* Wv8  = (const float*)d_in[12];
  const float* rsm  = (const float*)d_in[13];
  const float* rs2  = (const float*)d_in[14];
  const float* rs4  = (const float*)d_in[15];
  const float* Wproj= (const float*)d_in[17];
  const float* bproj= (const float*)d_in[18];
  const float* Wp1  = (const float*)d_in[19];
  const float* Wp2  = (const float*)d_in[20];
  float* out = (float*)d_out;

  char* ws = (char*)d_ws;
  // XT2 [0, 67,108,864): live pack->cov; dead afterwards, reused:
  //   POS [33.55M,50.33M)   (VM: tail in fused path)
  short* XT2  = (short*)(ws + 0);
  short* POS  = (short*)(ws + 33554432);

  const size_t NEEDF = 146425856;      // 16-copy covF + tail wT + tail VM
  int plain = (ws_size >= NEEDF) ? 1 : 0;

  float* covF; short* covB; float* Aout; short* QF; short* WvmB; short* WvT; float* wT; short* VM;
  if(plain){
    covF = (float*)(ws + 67108864);    // 16 * 3,670,016 = 58,720,256
    covB = (short*)(ws + 125829120);   // 1,835,008
    Aout = (float*)(ws + 127664128);   // 262,144
    QF   = (short*)(ws + 127926272);   // 1,048,576
    WvmB = (short*)(ws + 128974848);   // 131,072
    WvT  = (short*)(ws + 129105920);   // 524,288
    wT   = (float*)(ws + 129630208);   // 18,432
    VM   = (short*)(ws + 129648640);   // 16,777,216 -> end 146,425,856
  } else {
    covF = (float*)(ws + 67108864);
    covB = (short*)(ws + 70778880);
    Aout = (float*)(ws + 72613888);
    QF   = (short*)(ws + 72876032);
    WvmB = (short*)(ws + 73924608);
    WvT  = (short*)(ws + 74055680);
    wT   = (float*)(ws + 50331648);    // dead-XT2 slice, written after k_cov
    VM   = (short*)(ws + 0);           // overlays XT2, written after k_cov
  }

  if(!plain) hipMemsetAsync(covF, 0, 3670016, stream);
  if(plain){
    k_prep<<<1298, 256, 0, stream>>>(Wvm, Wv2, Wv4, Wv8, Wp1, Wp2, WvmB, WvT, wT);
    k_packy<<<dim3(256,1,2), 256, 0, stream>>>(y, WvmB, XT2, VM);
    k_pack <<<dim3(256,1,6), 256, 0, stream>>>(x2, x4, x8, y, XT2, 2);
  } else {
    k_cvt<<<256, 256, 0, stream>>>(Wvm, WvmB, 65536);
    k_wvt<<<1024, 256, 0, stream>>>(Wvm, Wv2, Wv4, Wv8, WvT);
    k_pack<<<dim3(256,1,8), 256, 0, stream>>>(x2, x4, x8, y, XT2, 0);
  }
  k_cov  <<<dim3(14,16), 512, 0, stream>>>(XT2, covF, plain);
  k_cvtN <<<3584, 256, 0, stream>>>(covF, covB, 917504, plain ? 16 : 1);
  if(!plain) k_wT<<<18, 256, 0, stream>>>(Wp1, Wp2, wT);   // overlays dead XT2 slice
  k_attn <<<dim3(8,2,4), 256, 0, stream>>>(Wq, Wkm, Wk2, Wk4, Wk8, rsm, rs2, rs4, covB, Aout);
  k_qfold<<<dim3(8,2,4), 256, 0, stream>>>(Wproj, Aout, WvT, QF);
  if(!plain) k_vm<<<512, 256, 0, stream>>>(y, WvmB, VM);
  k_convf<<<dim3(32,32,2), 512, 0, stream>>>(VM, wT, POS);
  k_final<<<512, 256, 0, stream>>>(y, x2, x4, x8, QF, bproj, POS, out);
}

// Round 22
// 240.747 us; speedup vs baseline: 1.0284x; 1.0284x over previous
//
#include <hip/hip_runtime.h>
#include <hip/hip_bf16.h>
#include <math.h>

// Problem constants: B=2, H=W=128, C=256, HEADS=8, D=32, N=16384, M=B*N=32768
typedef short bf16x8 __attribute__((ext_vector_type(8)));
typedef float f32x4 __attribute__((ext_vector_type(4)));

#define MFMA16(a,b,c) __builtin_amdgcn_mfma_f32_16x16x32_bf16(a,b,c,0,0,0)

__device__ inline short f2bf(float f){
  union{ __hip_bfloat16 h; short s; } u;
  u.h = __float2bfloat16(f);
  return u.s;
}
__device__ inline float bf2f(short s){
  uint32_t u = ((uint32_t)(uint16_t)s) << 16;
  return __builtin_bit_cast(float, u);
}
__device__ inline void store8bf(short* dst, float4 a, float4 b){
  union{ short s[8]; int4 q; } u;
  u.s[0]=f2bf(a.x); u.s[1]=f2bf(a.y); u.s[2]=f2bf(a.z); u.s[3]=f2bf(a.w);
  u.s[4]=f2bf(b.x); u.s[5]=f2bf(b.y); u.s[6]=f2bf(b.z); u.s[7]=f2bf(b.w);
  *(int4*)dst = u.q;
}

// async global->LDS, 16B per lane. LDS dest must be wave-uniform; HW adds lane*16.
__device__ inline void gld16(const void* g, void* l){
  __builtin_amdgcn_global_load_lds(
      (const __attribute__((address_space(1))) unsigned int*)g,
      (__attribute__((address_space(3))) unsigned int*)l, 16, 0, 0);
}

// raw barrier without vmcnt(0) drain; asm memory clobbers pin compiler ordering
#define BARC() do{ asm volatile("":::"memory"); __builtin_amdgcn_s_barrier(); \
                   asm volatile("":::"memory"); }while(0)

// ---------- generic f32 -> bf16 convert (fallback path) ----------
__global__ __launch_bounds__(256) void k_cvt(const float* __restrict__ src, short* __restrict__ dst, int n){
  int i = blockIdx.x*256 + threadIdx.x;
  if(i < n) dst[i] = f2bf(src[i]);
}

// ---------- sum ncpy cov copies (stride 917504 floats) -> bf16 ----------
__global__ __launch_bounds__(256) void k_cvtN(const float* __restrict__ src, short* __restrict__ dst,
                                              int n, int ncpy){
  int i = blockIdx.x*256 + threadIdx.x;
  if(i >= n) return;
  float s = src[i];
  for(int c=1;c<ncpy;++c) s += src[i + (size_t)c*917504];
  dst[i] = f2bf(s);
}

// ---------- transpose-convert the 4 Wv matrices (fallback path) ----------
__global__ __launch_bounds__(256) void k_wvt(const float* __restrict__ wm, const float* __restrict__ w2,
                                             const float* __restrict__ w4, const float* __restrict__ w8,
                                             short* __restrict__ wvT){
  int t = blockIdx.x*256 + threadIdx.x;      // 4*65536 total
  int br = t >> 16; int rem = t & 65535; int a = rem >> 8, j = rem & 255;
  const float* w = (br==0)? wm : (br==1)? w2 : (br==2)? w4 : w8;
  wvT[t] = f2bf(w[j*256 + a]);
}

// ---------- transpose conv weights (fallback path) ----------
__global__ __launch_bounds__(256) void k_wT(const float* __restrict__ w1, const float* __restrict__ w2,
                                            float* __restrict__ wT){
  int t = blockIdx.x*256 + threadIdx.x;      // 2*9*256 = 4608
  if(t >= 4608) return;
  int cv = t / 2304; int rem = t % 2304; int tap = rem >> 8; int c = rem & 255;
  const float* w = cv ? w2 : w1;
  wT[t] = w[c*9 + tap];
}

// ---------- merged prep: WvmB cvt (blocks 0..255), WvT transpose (256..1279), wT (1280..1297) ----------
__global__ __launch_bounds__(256) void k_prep(const float* __restrict__ Wvm, const float* __restrict__ Wv2,
                                              const float* __restrict__ Wv4, const float* __restrict__ Wv8,
                                              const float* __restrict__ Wp1, const float* __restrict__ Wp2,
                                              short* __restrict__ WvmB, short* __restrict__ wvT,
                                              float* __restrict__ wT){
  int bx = blockIdx.x, t = threadIdx.x;
  if(bx < 256){
    int i = bx*256 + t;
    WvmB[i] = f2bf(Wvm[i]);
  } else if(bx < 1280){
    int i = (bx-256)*256 + t;                // 0..262143
    int br = i >> 16; int rem = i & 65535; int a = rem >> 8, j = rem & 255;
    const float* w = (br==0)? Wvm : (br==1)? Wv2 : (br==2)? Wv4 : Wv8;
    wvT[i] = f2bf(w[j*256 + a]);
  } else {
    int i = (bx-1280)*256 + t;               // 0..4607
    if(i < 4608){
      int cv = i / 2304; int rem = i % 2304; int tap = rem >> 8; int c = rem & 255;
      const float* w = cv ? Wp2 : Wp1;
      wT[i] = w[c*9 + tap];
    }
  }
}

// ---------- swizzled LDS helpers for [64][256] bf16 A-tiles ----------
__device__ inline void at_write4(short* base, int row, int l, float4 v){
  union{ short s[4]; int2 q; } u;
  u.s[0]=f2bf(v.x); u.s[1]=f2bf(v.y); u.s[2]=f2bf(v.z); u.s[3]=f2bf(v.w);
  int byte = row*512 + 8*l;
  byte ^= ((row&7)<<4);
  *(int2*)((char*)base + byte) = u.q;
}
// column variant: c4 = column in units of 4 bf16
__device__ inline void at_write4c(short* base, int row, int c4, float4 v){
  union{ short s[4]; int2 q; } u;
  u.s[0]=f2bf(v.x); u.s[1]=f2bf(v.y); u.s[2]=f2bf(v.z); u.s[3]=f2bf(v.w);
  int byte = row*512 + c4*8;
  byte ^= ((row&7)<<4);
  *(int2*)((char*)base + byte) = u.q;
}
__device__ inline bf16x8 at_read8(const short* base, int row, int kk, int q){
  int byte = row*512 + kk*64 + q*16;
  byte ^= ((row&7)<<4);
  return *(const bf16x8*)((const char*)base + byte);
}

// ---------- pack x-inputs to tiled layout XT2[sb][ntile][256c][32n] bf16, 16KB tiles ----------
// TWO tiles per block (64 rows). Register transpose -> LDS staging at final tile layout
// (LDS-only XOR swizzle byte^=((byte>>8)&7)<<4 on BOTH write and read) -> linear coalesced
// copy-out. Global layout: chunk pos = hi ^ ((c>>1)&3) within each 64B c-row.
__global__ __launch_bounds__(256) void k_pack(const float* __restrict__ x2, const float* __restrict__ x4,
                                              const float* __restrict__ x8, const float* __restrict__ y,
                                              short* __restrict__ xt, int sb0){
  int sb = blockIdx.z + sb0; int s = sb >> 1, b = sb & 1;
  const float* src = ((s==0)? y : (s==1)? x2 : (s==2)? x4 : x8) + (size_t)b*16384*256;
  __shared__ int4 tile4[2048];               // 2 x 16KB
  char* tile = (char*)tile4;
  int t = threadIdx.x;
  int cg = t & 63, ng = t >> 6;              // channel group (4c), n-subgroup (8n)
  int n0 = blockIdx.x*64;
  const float* p0 = src + (size_t)(n0 + ng*8)*256 + cg*4;
  const float* p1 = src + (size_t)(n0 + 32 + ng*8)*256 + cg*4;
  union{ float4 q; float f[4]; } v0[8], v1[8];
  #pragma unroll
  for(int r=0;r<8;++r) v0[r].q = *(const float4*)(p0 + (size_t)r*256);
  #pragma unroll
  for(int r=0;r<8;++r) v1[r].q = *(const float4*)(p1 + (size_t)r*256);
  #pragma unroll
  for(int i=0;i<4;++i){
    int c = cg*4 + i;
    int byte = c*64 + ((ng ^ ((c>>1)&3))<<4);
    byte ^= ((byte>>8)&7)<<4;                // LDS-only swizzle (bits 8-10; tile base bit14 unaffected)
    union{ short s8[8]; int4 q; } u;
    #pragma unroll
    for(int r=0;r<8;++r) u.s8[r] = f2bf(v0[r].f[i]);
    *(int4*)(tile + byte) = u.q;
    #pragma unroll
    for(int r=0;r<8;++r) u.s8[r] = f2bf(v1[r].f[i]);
    *(int4*)(tile + 16384 + byte) = u.q;
  }
  __syncthreads();
  short* outb = xt + ((size_t)sb*512 + blockIdx.x*2)*8192;
  #pragma unroll
  for(int ti=0; ti<2; ++ti)
    #pragma unroll
    for(int j=0;j<4;++j){
      int addr = j*4096 + t*16;
      int sa = addr ^ (((addr>>8)&7)<<4);
      *(int4*)((char*)outb + ti*16384 + addr) = *(const int4*)(tile + ti*16384 + sa);
    }
}

// ---------- pack y + fused vm = y @ Wvm^T ----------
__global__ __launch_bounds__(256) void k_packy(const float* __restrict__ y, const short* __restrict__ wB,
                                               short* __restrict__ xt, short* __restrict__ vm){
  int b = blockIdx.z;
  const float* src = y + (size_t)b*16384*256;
  __shared__ int4 tile4[2048];               // 2 x 16KB cov-layout tiles
  __shared__ short at[64*256];               // 32KB [n][c] tile
  char* tile = (char*)tile4;
  int t = threadIdx.x;
  int cg = t & 63, ng = t >> 6;
  int n0 = blockIdx.x*64;
  const float* p0 = src + (size_t)(n0 + ng*8)*256 + cg*4;
  const float* p1 = src + (size_t)(n0 + 32 + ng*8)*256 + cg*4;
  union{ float4 q; float f[4]; } v0[8], v1[8];
  #pragma unroll
  for(int r=0;r<8;++r) v0[r].q = *(const float4*)(p0 + (size_t)r*256);
  #pragma unroll
  for(int r=0;r<8;++r) v1[r].q = *(const float4*)(p1 + (size_t)r*256);
  #pragma unroll
  for(int i=0;i<4;++i){
    int c = cg*4 + i;
    int byte = c*64 + ((ng ^ ((c>>1)&3))<<4);
    byte ^= ((byte>>8)&7)<<4;
    union{ short s8[8]; int4 q; } u;
    #pragma unroll
    for(int r=0;r<8;++r) u.s8[r] = f2bf(v0[r].f[i]);
    *(int4*)(tile + byte) = u.q;
    #pragma unroll
    for(int r=0;r<8;++r) u.s8[r] = f2bf(v1[r].f[i]);
    *(int4*)(tile + 16384 + byte) = u.q;
  }
  #pragma unroll
  for(int r=0;r<8;++r){
    at_write4c(at, ng*8 + r, cg, v0[r].q);
    at_write4c(at, 32 + ng*8 + r, cg, v1[r].q);
  }
  __syncthreads();
  // XT2 copy-out
  short* outb = xt + ((size_t)b*512 + blockIdx.x*2)*8192;
  #pragma unroll
  for(int ti=0; ti<2; ++ti)
    #pragma unroll
    for(int j=0;j<4;++j){
      int addr = j*4096 + t*16;
      int sa = addr ^ (((addr>>8)&7)<<4);
      *(int4*)((char*)outb + ti*16384 + addr) = *(const int4*)(tile + ti*16384 + sa);
    }
  // vm compute (k_vm body)
  int l = t & 63, w = t >> 6;
  size_t m0 = (size_t)b*16384 + n0;
  f32x4 acc[4][4];
  #pragma unroll
  for(int i=0;i<4;++i)
    #pragma unroll
    for(int n2=0;n2<4;++n2) acc[i][n2] = (f32x4){0.f,0.f,0.f,0.f};
  #pragma unroll
  for(int kk=0; kk<8; ++kk){
    bf16x8 a[4];
    #pragma unroll
    for(int rt=0;rt<4;++rt) a[rt] = at_read8(at, rt*16 + (l&15), kk, l>>4);
    #pragma unroll
    for(int nt=0;nt<4;++nt){
      int bc = (w*4+nt)*16 + (l&15);
      bf16x8 bb = *(const bf16x8*)&wB[(size_t)bc*256 + kk*32 + 8*(l>>4)];
      #pragma unroll
      for(int rt=0;rt<4;++rt) acc[rt][nt] = MFMA16(a[rt], bb, acc[rt][nt]);
    }
  }
  #pragma unroll
  for(int rt=0;rt<4;++rt)
    #pragma unroll
    for(int nt=0;nt<4;++nt)
      #pragma unroll
      for(int r=0;r<4;++r){
        size_t row = m0 + rt*16 + 4*(l>>4) + r;
        int col = (w*4+nt)*16 + (l&15);
        vm[row*256 + col] = f2bf(acc[rt][nt][r]);
      }
}

// fragment read from a staged 16KB tile (swizzle pre-applied by pack)
__device__ inline bf16x8 tfrag(const short* base, int c, int hi){
  int byte = c*64 + ((hi ^ ((c>>1)&3))<<4);
  return *(const bf16x8*)((const char*)base + byte);
}

// ---------- gram jobs: cov[jb][U_ch][V_ch] = sum_n U[n,i] V[n,j], from tiled XT2 ----------
__global__ __launch_bounds__(512) void k_cov(const short* __restrict__ xt, float* __restrict__ covF,
                                             int plain){
  int jb = blockIdx.x;               // 0..13
  int ck = blockIdx.y;               // 0..15 : n-chunk of 1024 (16 phases of 2 tiles)
  int j = jb >> 1, b = jb & 1;
  int t = threadIdx.x, l = t & 63, w = t >> 6;
  int lr = l & 15, hi = l >> 4;
  int wr = w >> 1, wc = w & 1;       // wave row-group (64 rows), col-group (128 cols)
  __shared__ short lds2[2][32768];   // 2 phase-buffers x (2 tiles x 16KB) = 128KB
  int su = (j < 4) ? 0 : (j - 3);
  int sv = (j == 0) ? 0 : ((j < 4) ? j : (j - 3));
  int sym = (su == sv);
  const short* Ug = xt + (size_t)(su*2+b)*512*8192;
  const short* Vg = xt + (size_t)(sv*2+b)*512*8192;
  int nt0 = ck*32;

  f32x4 acc[4][8];
  #pragma unroll
  for(int i=0;i<4;++i)
    #pragma unroll
    for(int n2=0;n2<8;++n2) acc[i][n2] = (f32x4){0.f,0.f,0.f,0.f};

  #define STAGE_T_S(bufi, tt, kk) do{                                           \
    const short* Ut_ = Ug + (size_t)(nt0+(kk))*8192;                            \
    short* dst_ = &lds2[bufi][(tt)*16384];                                      \
    _Pragma("unroll")                                                           \
    for(int i_=0;i_<2;++i_){ int ch_ = w*2+i_;                                  \
      gld16(Ut_ + ch_*512 + l*8, dst_ + ch_*512); }                             \
  }while(0)
  #define STAGE_T_A(bufi, tt, kk) do{                                           \
    const short* Ut_ = Ug + (size_t)(nt0+(kk))*8192;                            \
    const short* Vt_ = Vg + (size_t)(nt0+(kk))*8192;                            \
    short* dst_ = &lds2[bufi][(tt)*16384];                                      \
    _Pragma("unroll")                                                           \
    for(int i_=0;i_<4;++i_){ int ch_ = w*4+i_;                                  \
      const short* g_ = (ch_<16) ? (Ut_ + ch_*512 + l*8)                        \
                                 : (Vt_ + (ch_-16)*512 + l*8);                  \
      gld16(g_, dst_ + ch_*512); }                                              \
  }while(0)
  #define COMPUTE_T(bufp, vofs) do{                                             \
    const short* Ub_ = bufp;                                                    \
    const short* Vb_ = Ub_ + (vofs);                                            \
    bf16x8 a_[4];                                                               \
    _Pragma("unroll")                                                           \
    for(int rt_=0;rt_<4;++rt_)                                                  \
      a_[rt_] = tfrag(Ub_, wr*64 + rt_*16 + lr, hi);                            \
    _Pragma("unroll")                                                           \
    for(int nt_=0;nt_<8;++nt_){                                                 \
      bf16x8 bb_ = tfrag(Vb_, wc*128 + nt_*16 + lr, hi);                        \
      _Pragma("unroll")                                                         \
      for(int rt_=0;rt_<4;++rt_)                                                \
        acc[rt_][nt_] = MFMA16(a_[rt_], bb_, acc[rt_][nt_]);                    \
    }                                                                           \
  }while(0)

  if(sym){
    STAGE_T_S(0,0,0); STAGE_T_S(0,1,1); STAGE_T_S(1,0,2); STAGE_T_S(1,1,3);
    asm volatile("s_waitcnt vmcnt(4)":::"memory");   // phase0 landed; phase1 in flight
    BARC();
    #pragma unroll 1
    for(int p=0;p<16;++p){
      const short* base = &lds2[p&1][0];
      COMPUTE_T(base, 0);
      COMPUTE_T(base + 16384, 0);
      if(p==15) break;
      BARC();
      if(p < 14){
        STAGE_T_S(p&1, 0, 2*p+4); STAGE_T_S(p&1, 1, 2*p+5);
        asm volatile("s_waitcnt vmcnt(4)":::"memory");   // phase p+1 landed
      } else {
        asm volatile("s_waitcnt vmcnt(0)":::"memory");
      }
      BARC();
    }
  } else {
    STAGE_T_A(0,0,0); STAGE_T_A(0,1,1); STAGE_T_A(1,0,2); STAGE_T_A(1,1,3);
    asm volatile("s_waitcnt vmcnt(8)":::"memory");
    BARC();
    #pragma unroll 1
    for(int p=0;p<16;++p){
      const short* base = &lds2[p&1][0];
      COMPUTE_T(base, 8192);
      COMPUTE_T(base + 16384, 8192);
      if(p==15) break;
      BARC();
      if(p < 14){
        STAGE_T_A(p&1, 0, 2*p+4); STAGE_T_A(p&1, 1, 2*p+5);
        asm volatile("s_waitcnt vmcnt(8)":::"memory");
      } else {
        asm volatile("s_waitcnt vmcnt(0)":::"memory");
      }
      BARC();
    }
  }
  #undef STAGE_T_S
  #undef STAGE_T_A
  #undef COMPUTE_T

  if(plain){
    float* cov = covF + (size_t)ck*917504 + (size_t)jb*65536;
    #pragma unroll
    for(int rt=0;rt<4;++rt)
      #pragma unroll
      for(int nt=0;nt<8;++nt)
        #pragma unroll
        for(int r=0;r<4;++r){
          int row = wr*64 + rt*16 + 4*hi + r;
          int col = wc*128 + nt*16 + lr;
          cov[(size_t)row*256 + col] = acc[rt][nt][r];
        }
  } else {
    float* cov = covF + (size_t)jb*65536;
    #pragma unroll
    for(int rt=0;rt<4;++rt)
      #pragma unroll
      for(int nt=0;nt<8;++nt)
        #pragma unroll
        for(int r=0;r<4;++r){
          int row = wr*64 + rt*16 + 4*hi + r;
          int col = wc*128 + nt*16 + lr;
          atomicAdd(&cov[(size_t)row*256 + col], acc[rt][nt][r]);
        }
  }
}

// ---------- helpers for 32x256 and 32x32 MFMA products in k_attn ----------
__device__ inline void mm_32x256(const short (*wA)[264], const short* __restrict__ covbf,
                                 short (*tmp)[264], int t){
  int l = t & 63, w = t >> 6;
  int mt = w >> 1, ntb = (w & 1)*8;
  f32x4 acc[8];
  #pragma unroll
  for(int i=0;i<8;++i) acc[i] = (f32x4){0.f,0.f,0.f,0.f};
  #pragma unroll
  for(int kk=0; kk<8; ++kk){
    bf16x8 a = *(const bf16x8*)&wA[16*mt + (l&15)][kk*32 + 8*(l>>4)];
    #pragma unroll
    for(int n=0; n<8; ++n){
      int j = (ntb+n)*16 + (l&15);
      bf16x8 bb = *(const bf16x8*)&covbf[(size_t)j*256 + kk*32 + 8*(l>>4)];
      acc[n] = MFMA16(a, bb, acc[n]);
    }
  }
  #pragma unroll
  for(int n=0;n<8;++n)
    #pragma unroll
    for(int r=0;r<4;++r)
      tmp[16*mt + 4*(l>>4) + r][(ntb+n)*16 + (l&15)] = f2bf(acc[n][r]);
}
__device__ inline void mm_32x32(const short (*A)[264], const short (*Bw)[264], float (*M)[33], int t){
  int l = t & 63, w = t >> 6;
  int mt = w >> 1, nt = w & 1;
  f32x4 acc = (f32x4){0.f,0.f,0.f,0.f};
  #pragma unroll
  for(int kk=0; kk<8; ++kk){
    bf16x8 a = *(const bf16x8*)&A[16*mt + (l&15)][kk*32 + 8*(l>>4)];
    bf16x8 b = *(const bf16x8*)&Bw[16*nt + (l&15)][kk*32 + 8*(l>>4)];
    acc = MFMA16(a, b, acc);
  }
  #pragma unroll
  for(int r=0;r<4;++r)
    M[16*mt + 4*(l>>4) + r][16*nt + (l&15)] = acc[r];
}

// ---------- attention matrices: G = Wk_h * Cov_xy * Wq_h^T, norms from Cxx/Cyy diag, softmax -> A ----------
__global__ __launch_bounds__(256) void k_attn(
    const float* __restrict__ Wq, const float* __restrict__ Wkm, const float* __restrict__ Wk2,
    const float* __restrict__ Wk4, const float* __restrict__ Wk8,
    const float* __restrict__ rsm, const float* __restrict__ rs2, const float* __restrict__ rs4,
    const short* __restrict__ covB, float* __restrict__ Aout){
  int h = blockIdx.x, b = blockIdx.y, br = blockIdx.z;
  int t = threadIdx.x;
  __shared__ short wk[32][264], wq[32][264], tmp[32][264];
  __shared__ float Ml[32][33];
  __shared__ float nrm[64];
  const float* Wk = (br==0)? Wkm : (br==1)? Wk2 : (br==2)? Wk4 : Wk8;
  {
    int d = t >> 3, c0 = (t & 7)*32;
    const float* pk = Wk + (size_t)(h*32+d)*256 + c0;
    const float* pq = Wq + (size_t)(h*32+d)*256 + c0;
    #pragma unroll
    for(int i=0;i<32;i+=8){
      float4 a1 = *(const float4*)(pk+i), a2 = *(const float4*)(pk+i+4);
      store8bf(&wk[d][c0+i], a1, a2);
      float4 b1 = *(const float4*)(pq+i), b2 = *(const float4*)(pq+i+4);
      store8bf(&wq[d][c0+i], b1, b2);
    }
  }
  __syncthreads();
  const short* cxy = covB + (size_t)(br*2+b)*65536;
  const short* cxx = (br==0)? cxy : covB + (size_t)(8 + (br-1)*2 + b)*65536;
  const short* cyy = covB + (size_t)b*65536;
  // k norms^2
  mm_32x256(wk, cxx, tmp, t); __syncthreads();
  mm_32x32(tmp, wk, Ml, t);   __syncthreads();
  if(t < 32) nrm[t] = Ml[t][t];
  __syncthreads();
  // q norms^2
  mm_32x256(wq, cyy, tmp, t); __syncthreads();
  mm_32x32(tmp, wq, Ml, t);   __syncthreads();
  if(t < 32) nrm[32+t] = Ml[t][t];
  __syncthreads();
  // G
  mm_32x256(wk, cxy, tmp, t); __syncthreads();
  mm_32x32(tmp, wq, Ml, t);   __syncthreads();
  if(t < 32){
    int d = t;
    const float* rs = (br==0)? rsm : (br==1)? rs2 : rs4;  // br==3 uses rescale4 (faithful to source)
    float rsv = rs[h];
    float invk = 1.f / fmaxf(sqrtf(fmaxf(nrm[d], 0.f)), 1e-12f);
    float lg[32]; float mx = -1e30f;
    #pragma unroll
    for(int e=0;e<32;++e){
      float invq = 1.f / fmaxf(sqrtf(fmaxf(nrm[32+e], 0.f)), 1e-12f);
      float v = Ml[d][e] * invk * invq * rsv;
      lg[e] = v; mx = fmaxf(mx, v);
    }
    float sum = 0.f;
    #pragma unroll
    for(int e=0;e<32;++e){ lg[e] = expf(lg[e]-mx); sum += lg[e]; }
    float inv = 1.f/sum;
    float* Ao = Aout + ((size_t)((br*2+b)*8 + h))*1024 + d*32;
    #pragma unroll
    for(int e=0;e<32;++e) Ao[e] = lg[e]*inv;
  }
}

// ---------- fold: Qf[br][b] = (Wproj ⊙head A) * Wv_br   (256x256 bf16 each) ----------
__global__ __launch_bounds__(256) void k_qfold(const float* __restrict__ Wproj, const float* __restrict__ Ain,
                                               const short* __restrict__ wvT, short* __restrict__ qf){
  int cg = blockIdx.x, b = blockIdx.y, br = blockIdx.z;
  int t = threadIdx.x;
  __shared__ float Al[8*1036];
  __shared__ short pl[32][264];
  const float* Ag = Ain + (size_t)((br*2+b)*8)*1024;
  for(int i=t; i<8192; i+=256){
    int hh = i >> 10, dd = (i >> 5) & 31, ee = i & 31;
    Al[hh*1036 + dd*32 + ee] = Ag[i];
  }
  __syncthreads();
  {
    int c = cg*32 + (t >> 3), h = t & 7;
    const float* wpr = Wproj + (size_t)c*256 + h*32;
    float wp[32];
    #pragma unroll
    for(int i=0;i<32;i+=4){
      float4 v = *(const float4*)(wpr+i);
      wp[i]=v.x; wp[i+1]=v.y; wp[i+2]=v.z; wp[i+3]=v.w;
    }
    float pv[32];
    #pragma unroll
    for(int e=0;e<32;++e) pv[e]=0.f;
    const float* Ah = Al + h*1036;
    #pragma unroll
    for(int d=0; d<32; ++d){
      float wpd = wp[d];
      #pragma unroll
      for(int e=0;e<32;e+=4){
        float4 av = *(const float4*)&Ah[d*32+e];
        pv[e]   += wpd*av.x; pv[e+1] += wpd*av.y;
        pv[e+2] += wpd*av.z; pv[e+3] += wpd*av.w;
      }
    }
    #pragma unroll
    for(int e=0;e<32;++e) pl[t>>3][h*32+e] = f2bf(pv[e]);
  }
  __syncthreads();
  {
    int l = t & 63, w = t >> 6, mt = w >> 1, ntb = (w & 1)*8;
    const short* wvt = wvT + (size_t)br*65536;
    f32x4 acc[8];
    #pragma unroll
    for(int i=0;i<8;++i) acc[i] = (f32x4){0.f,0.f,0.f,0.f};
    #pragma unroll
    for(int kk=0; kk<8; ++kk){
      bf16x8 a = *(const bf16x8*)&pl[16*mt + (l&15)][kk*32 + 8*(l>>4)];
      #pragma unroll
      for(int n=0;n<8;++n){
        int arow = (ntb+n)*16 + (l&15);
        bf16x8 bb = *(const bf16x8*)&wvt[(size_t)arow*256 + kk*32 + 8*(l>>4)];
        acc[n] = MFMA16(a, bb, acc[n]);
      }
    }
    short* qfp = qf + (size_t)(br*2+b)*65536;
    #pragma unroll
    for(int n=0;n<8;++n)
      #pragma unroll
      for(int r=0;r<4;++r){
        int row = cg*32 + 16*mt + 4*(l>>4) + r;
        int col = (ntb+n)*16 + (l&15);
        qfp[(size_t)row*256 + col] = f2bf(acc[n][r]);
      }
  }
}

// ---------- vm = y @ Wvm^T  (fallback path) ----------
__global__ __launch_bounds__(256,2) void k_vm(const float* __restrict__ y, const short* __restrict__ wB,
                                              short* __restrict__ vm){
  int t = threadIdx.x, l = t & 63, w = t >> 6;
  size_t m0 = (size_t)blockIdx.x*64;
  __shared__ short at[64*256];
  #pragma unroll
  for(int rr=0; rr<16; ++rr){
    int row = w*16 + rr;
    float4 v = *(const float4*)(y + (m0+row)*256 + 4*l);
    at_write4(at, row, l, v);
  }
  __syncthreads();
  f32x4 acc[4][4];
  #pragma unroll
  for(int i=0;i<4;++i)
    #pragma unroll
    for(int n2=0;n2<4;++n2) acc[i][n2] = (f32x4){0.f,0.f,0.f,0.f};
  #pragma unroll
  for(int kk=0; kk<8; ++kk){
    bf16x8 a[4];
    #pragma unroll
    for(int rt=0;rt<4;++rt) a[rt] = at_read8(at, rt*16 + (l&15), kk, l>>4);
    #pragma unroll
    for(int nt=0;nt<4;++nt){
      int bc = (w*4+nt)*16 + (l&15);
      bf16x8 bb = *(const bf16x8*)&wB[(size_t)bc*256 + kk*32 + 8*(l>>4)];
      #pragma unroll
      for(int rt=0;rt<4;++rt) acc[rt][nt] = MFMA16(a[rt], bb, acc[rt][nt]);
    }
  }
  #pragma unroll
  for(int rt=0;rt<4;++rt)
    #pragma unroll
    for(int nt=0;nt<4;++nt)
      #pragma unroll
      for(int r=0;r<4;++r){
        size_t row = m0 + rt*16 + 4*(l>>4) + r;
        int col = (w*4+nt)*16 + (l&15);
        vm[row*256 + col] = f2bf(acc[rt][nt][r]);
      }
}

// ---------- depthwise 3x3 conv (NHWC), transposed coalesced weights, optional exact GELU ----------
__global__ __launch_bounds__(256) void k_conv(const short* __restrict__ in, const float* __restrict__ wT,
                                              short* __restrict__ out, int do_gelu){
  int tid = blockIdx.x*256 + threadIdx.x;
  int cg = tid & 31; int pix = tid >> 5;
  int x = pix & 127, yy = (pix >> 7) & 127, b = pix >> 14;
  int c0 = cg*8;
  float acc[8];
  #pragma unroll
  for(int i=0;i<8;++i) acc[i]=0.f;
  #pragma unroll
  for(int ky=0; ky<3; ++ky){
    int sy = yy + ky - 1;
    if(sy < 0 || sy > 127) continue;
    #pragma unroll
    for(int kx=0; kx<3; ++kx){
      int sx = x + kx - 1;
      if(sx < 0 || sx > 127) continue;
      const float* wp = wT + (ky*3+kx)*256 + c0;
      float4 w0 = *(const float4*)wp;
      float4 w1 = *(const float4*)(wp+4);
      const short* p = in + ((size_t)(((b<<7)+sy)<<7) + sx)*256 + c0;
      union{ int4 q; short s[8]; } u;
      u.q = *(const int4*)p;
      acc[0] += bf2f(u.s[0])*w0.x; acc[1] += bf2f(u.s[1])*w0.y;
      acc[2] += bf2f(u.s[2])*w0.z; acc[3] += bf2f(u.s[3])*w0.w;
      acc[4] += bf2f(u.s[4])*w1.x; acc[5] += bf2f(u.s[5])*w1.y;
      acc[6] += bf2f(u.s[6])*w1.z; acc[7] += bf2f(u.s[7])*w1.w;
    }
  }
  if(do_gelu){
    #pragma unroll
    for(int cc=0;cc<8;++cc)
      acc[cc] = 0.5f*acc[cc]*(1.f + erff(acc[cc]*0.70710678118654752f));
  }
  union{ int4 q; short s[8]; } o;
  #pragma unroll
  for(int cc=0;cc<8;++cc) o.s[cc] = f2bf(acc[cc]);
  *(int4*)(out + (size_t)pix*256 + c0) = o.q;
}

// ---------- final: out = sum_br x_br @ Qf[br][b]^T + bproj + pos ----------
// Double-buffered LDS + register prefetch of next branch; ONE raw barrier per branch
// (lgkmcnt(0) only -- global prefetch stays in flight across the barrier).
__global__ __launch_bounds__(256,2) void k_final(const float* __restrict__ y, const float* __restrict__ x2,
                                                 const float* __restrict__ x4, const float* __restrict__ x8,
                                                 const short* __restrict__ qf, const float* __restrict__ bproj,
                                                 const short* __restrict__ pos, float* __restrict__ out){
  int t = threadIdx.x, l = t & 63, w = t >> 6;
  size_t m0 = (size_t)blockIdx.x*64;
  int b = (int)(m0 >> 14);
  __shared__ short at2[2][64*256];
  f32x4 acc[4][4];
  #pragma unroll
  for(int i=0;i<4;++i)
    #pragma unroll
    for(int n2=0;n2<4;++n2) acc[i][n2] = (f32x4){0.f,0.f,0.f,0.f};
  const float* srcs[4] = {y, x2, x4, x8};
  float4 vreg[16];
  #pragma unroll
  for(int rr=0; rr<16; ++rr)
    vreg[rr] = *(const float4*)(srcs[0] + (m0 + w*16 + rr)*256 + 4*l);
  #pragma unroll 1
  for(int br=0; br<4; ++br){
    short* buf = &at2[br&1][0];
    #pragma unroll
    for(int rr=0; rr<16; ++rr)
      at_write4(buf, w*16 + rr, l, vreg[rr]);
    if(br < 3){
      const float* s = srcs[br+1];
      #pragma unroll
      for(int rr=0; rr<16; ++rr)
        vreg[rr] = *(const float4*)(s + (m0 + w*16 + rr)*256 + 4*l);
    }
    asm volatile("s_waitcnt lgkmcnt(0)":::"memory");   // LDS writes visible
    BARC();                                            // no vmcnt drain: prefetch in flight
    const short* qb = qf + (size_t)(br*2+b)*65536;
    #pragma unroll
    for(int kk=0; kk<8; ++kk){
      bf16x8 a[4];
      #pragma unroll
      for(int rt=0;rt<4;++rt) a[rt] = at_read8(buf, rt*16 + (l&15), kk, l>>4);
      #pragma unroll
      for(int nt=0;nt<4;++nt){
        int bc = (w*4+nt)*16 + (l&15);
        bf16x8 bb = *(const bf16x8*)&qb[(size_t)bc*256 + kk*32 + 8*(l>>4)];
        #pragma unroll
        for(int rt=0;rt<4;++rt) acc[rt][nt] = MFMA16(a[rt], bb, acc[rt][nt]);
      }
    }
  }
  #pragma unroll
  for(int rt=0;rt<4;++rt)
    #pragma unroll
    for(int nt=0;nt<4;++nt)
      #pragma unroll
      for(int r=0;r<4;++r){
        size_t row = m0 + rt*16 + 4*(l>>4) + r;
        int col = (w*4+nt)*16 + (l&15);
        out[row*256 + col] = acc[rt][nt][r] + bproj[col] + bf2f(pos[row*256 + col]);
      }
}

extern "C" void kernel_launch(void* const* d_in, const int* in_sizes, int n_in,
                              void* d_out, int out_size, void* d_ws, size_t ws_size,
                              hipStream_t stream){
  (void)in_sizes; (void)n_in; (void)out_size;
  const float* x2   = (const float*)d_in[0];
  const float* x4   = (const float*)d_in[1];
  const float* x8   = (const float*)d_in[2];
  const float* y    = (const float*)d_in[3];
  const float* Wq   = (const float*)d_in[4];
  const float* Wkm  = (const float*)d_in[5];
  const float* Wvm  = (const float*)d_in[6];
  const float* Wk2  = (const float*)d_in[7];
  const float* Wv2  = (const float*)d_in[8];
  const float* Wk4  = (const float*)d_in[9];
  const float* Wv4  = (const float*)d_in[10];
  const float* Wk8  = (const float*)d_in[11];
  const float* Wv8  = (const float*)d_in[12];
  const float* rsm  = (const float*)d_in[13];
  const float* rs2  = (const float*)d_in[14];
  const float* rs4  = (const float*)d_in[15];
  const float* Wproj= (const float*)d_in[17];
  const float* bproj= (const float*)d_in[18];
  const float* Wp1  = (const float*)d_in[19];
  const float* Wp2  = (const float*)d_in[20];
  float* out = (float*)d_out;

  char* ws = (char*)d_ws;
  // XT2 [0, 67,108,864): live pack->cov; dead afterwards, reused:
  //   GBUF [16.78M,33.55M)  POS [33.55M,50.33M)   (VM: tail in fused path)
  short* XT2  = (short*)(ws + 0);
  short* GBUF = (short*)(ws + 16777216);
  short* POS  = (short*)(ws + 33554432);

  const size_t NEEDF = 146425856;      // 16-copy covF + tail wT + tail VM
  int plain = (ws_size >= NEEDF) ? 1 : 0;

  float* covF; short* covB; float* Aout; short* QF; short* WvmB; short* WvT; float* wT; short* VM;
  if(plain){
    covF = (float*)(ws + 67108864);    // 16 * 3,670,016 = 58,720,256
    covB = (short*)(ws + 125829120);   // 1,835,008
    Aout = (float*)(ws + 127664128);   // 262,144
    QF   = (short*)(ws + 127926272);   // 1,048,576
    WvmB = (short*)(ws + 128974848);   // 131,072
    WvT  = (short*)(ws + 129105920);   // 524,288
    wT   = (float*)(ws + 129630208);   // 18,432
    VM   = (short*)(ws + 129648640);   // 16,777,216 -> end 146,425,856
  } else {
    covF = (float*)(ws + 67108864);
    covB = (short*)(ws + 70778880);
    Aout = (float*)(ws + 72613888);
    QF   = (short*)(ws + 72876032);
    WvmB = (short*)(ws + 73924608);
    WvT  = (short*)(ws + 74055680);
    wT   = (float*)(ws + 50331648);    // dead-XT2 slice, written after k_cov
    VM   = (short*)(ws + 0);           // overlays XT2, written after k_cov
  }

  if(!plain) hipMemsetAsync(covF, 0, 3670016, stream);
  if(plain){
    k_prep<<<1298, 256, 0, stream>>>(Wvm, Wv2, Wv4, Wv8, Wp1, Wp2, WvmB, WvT, wT);
    k_packy<<<dim3(256,1,2), 256, 0, stream>>>(y, WvmB, XT2, VM);
    k_pack <<<dim3(256,1,6), 256, 0, stream>>>(x2, x4, x8, y, XT2, 2);
  } else {
    k_cvt<<<256, 256, 0, stream>>>(Wvm, WvmB, 65536);
    k_wvt<<<1024, 256, 0, stream>>>(Wvm, Wv2, Wv4, Wv8, WvT);
    k_pack<<<dim3(256,1,8), 256, 0, stream>>>(x2, x4, x8, y, XT2, 0);
  }
  k_cov  <<<dim3(14,16), 512, 0, stream>>>(XT2, covF, plain);
  k_cvtN <<<3584, 256, 0, stream>>>(covF, covB, 917504, plain ? 16 : 1);
  if(!plain) k_wT<<<18, 256, 0, stream>>>(Wp1, Wp2, wT);   // overlays dead XT2 slice
  k_attn <<<dim3(8,2,4), 256, 0, stream>>>(Wq, Wkm, Wk2, Wk4, Wk8, rsm, rs2, rs4, covB, Aout);
  k_qfold<<<dim3(8,2,4), 256, 0, stream>>>(Wproj, Aout, WvT, QF);
  if(!plain) k_vm<<<512, 256, 0, stream>>>(y, WvmB, VM);
  k_conv <<<4096, 256, 0, stream>>>(VM, wT, GBUF, 1);
  k_conv <<<4096, 256, 0, stream>>>(GBUF, wT + 2304, POS, 0);
  k_final<<<512, 256, 0, stream>>>(y, x2, x4, x8, QF, bproj, POS, out);
}